// Round 6
// baseline (13409.370 us; speedup 1.0000x reference)
//
#include <hip/hip_runtime.h>
#include <hip/hip_bf16.h>
#include <stdint.h>

// ---------------------------------------------------------------------------
// Tacotron2 decoder on MI355X — persistent pipelined recurrence, v6.
// v4 -> v6: ONE change — corrected P-ring allocation. v3/v4/v5 allocated
// 524,288 B per P ring ("2*64*4096*2" mis-multiplied); actual need is
// 1,048,576 B. P0 slot 1 aliased P1 slot 0, so role-1 reads raced role-2
// writes every even tick -> nondeterministic absmax 0.17-0.35 across
// R3/R4/R5. Staging design itself (per-XCD leader copy + sc0 consumer
// reads) is unchanged from v4 — this round is its clean test.
// ---------------------------------------------------------------------------

typedef short  bf16x8  __attribute__((ext_vector_type(8)));
typedef float  f32x16  __attribute__((ext_vector_type(16)));

// ---------------- threefry2x32 (exact JAX semantics) ------------------------
__device__ __forceinline__ uint32_t rotl32(uint32_t x, int r) {
  return (x << r) | (x >> (32 - r));
}

__device__ __forceinline__ void tf2x32(uint32_t k0, uint32_t k1,
                                       uint32_t x0, uint32_t x1,
                                       uint32_t& o0, uint32_t& o1) {
  uint32_t k2 = k0 ^ k1 ^ 0x1BD11BDAu;
  x0 += k0; x1 += k1;
#define TF_R(r) { x0 += x1; x1 = rotl32(x1, r); x1 ^= x0; }
  TF_R(13) TF_R(15) TF_R(26) TF_R(6)   x0 += k1; x1 += k2 + 1u;
  TF_R(17) TF_R(29) TF_R(16) TF_R(24)  x0 += k2; x1 += k0 + 2u;
  TF_R(13) TF_R(15) TF_R(26) TF_R(6)   x0 += k0; x1 += k1 + 3u;
  TF_R(17) TF_R(29) TF_R(16) TF_R(24)  x0 += k1; x1 += k2 + 4u;
  TF_R(13) TF_R(15) TF_R(26) TF_R(6)   x0 += k2; x1 += k0 + 5u;
#undef TF_R
  o0 = x0; o1 = x1;
}

__device__ __forceinline__ void dropout_keys(uint32_t& a1, uint32_t& b1,
                                             uint32_t& a2, uint32_t& b2) {
  uint32_t o0, o1, p0, p1;
  tf2x32(0u, 42u, 0u, 2u, o0, o1);
  tf2x32(0u, 42u, 1u, 3u, p0, p1);
  a1 = o0; b1 = p0;
  a2 = o1; b2 = p1;
}

__device__ __forceinline__ bool keep_mask(uint32_t ka, uint32_t kb, uint32_t e) {
  const uint32_t H = 4923392u;       // (601*64*256)/2
  uint32_t o0, o1;
  if (e < H) { tf2x32(ka, kb, e, e + H, o0, o1); return o0 < 0x80000000u; }
  else       { tf2x32(ka, kb, e - H, e, o0, o1); return o1 < 0x80000000u; }
}

__device__ __forceinline__ float sigf(float x)  { return 1.f / (1.f + __expf(-x)); }
__device__ __forceinline__ float tanhf2(float x){ return 2.f / (1.f + __expf(-2.f * x)) - 1.f; }

__device__ __forceinline__ short bf16bits(float f) {
  __hip_bfloat16 h = __float2bfloat16(f);
  short s; __builtin_memcpy(&s, &h, 2);
  return s;
}
__device__ __forceinline__ float bflo(uint32_t u) {
  uint32_t x = u << 16; float f; __builtin_memcpy(&f, &x, 4); return f;
}
__device__ __forceinline__ float bfhi(uint32_t u) {
  uint32_t x = u & 0xffff0000u; float f; __builtin_memcpy(&f, &x, 4); return f;
}

// ---- relaxed agent-scope (MALL-coherent, NO cache maintenance) accessors ---
__device__ __forceinline__ uint64_t ld_u64_a(const void* p) {
  return __hip_atomic_load((const uint64_t*)p, __ATOMIC_RELAXED, __HIP_MEMORY_SCOPE_AGENT);
}
__device__ __forceinline__ uint32_t ld_u32_a(const void* p) {
  return __hip_atomic_load((const uint32_t*)p, __ATOMIC_RELAXED, __HIP_MEMORY_SCOPE_AGENT);
}
__device__ __forceinline__ void st_u32_a(void* p, uint32_t v) {
  __hip_atomic_store((uint32_t*)p, v, __ATOMIC_RELAXED, __HIP_MEMORY_SCOPE_AGENT);
}

// ---- sc0 loads: bypass L1, served by this XCD's L2 (coherent vs same-XCD
// write-through stores). 8x16B fragment batch + single wait. ----------------
__device__ __forceinline__ void ld8_sc0(const __hip_bfloat16* p, bf16x8 (&d)[8]) {
  asm volatile(
      "global_load_dwordx4 %0, %8, off sc0\n\t"
      "global_load_dwordx4 %1, %8, off offset:32 sc0\n\t"
      "global_load_dwordx4 %2, %8, off offset:64 sc0\n\t"
      "global_load_dwordx4 %3, %8, off offset:96 sc0\n\t"
      "global_load_dwordx4 %4, %8, off offset:128 sc0\n\t"
      "global_load_dwordx4 %5, %8, off offset:160 sc0\n\t"
      "global_load_dwordx4 %6, %8, off offset:192 sc0\n\t"
      "global_load_dwordx4 %7, %8, off offset:224 sc0\n\t"
      "s_waitcnt vmcnt(0)"
      : "=&v"(d[0]), "=&v"(d[1]), "=&v"(d[2]), "=&v"(d[3]),
        "=&v"(d[4]), "=&v"(d[5]), "=&v"(d[6]), "=&v"(d[7])
      : "v"(p) : "memory");
}
__device__ __forceinline__ void ld4_u32_sc0(const __hip_bfloat16* p,
                                            uint32_t (&d)[4]) {
  asm volatile(
      "global_load_dword %0, %4, off sc0\n\t"
      "global_load_dword %1, %4, off offset:512 sc0\n\t"
      "global_load_dword %2, %4, off offset:1024 sc0\n\t"
      "global_load_dword %3, %4, off offset:1536 sc0\n\t"
      "s_waitcnt vmcnt(0)"
      : "=&v"(d[0]), "=&v"(d[1]), "=&v"(d[2]), "=&v"(d[3])
      : "v"(p) : "memory");
}

// ---------------- prenet layer 1 --------------------------------------------
__global__ void prenet1_kernel(const float* __restrict__ dec,
                               const float* __restrict__ Wp1,
                               float* __restrict__ pn1) {
  const int t = blockIdx.x;
  const int tid = threadIdx.x;
  __shared__ float          sdec[64][81];
  __shared__ __hip_bfloat16 sw1[256][80];
  for (int idx = tid; idx < 64 * 80; idx += 256) {
    int b = idx / 80, m = idx - b * 80;
    sdec[b][m] = (t == 0) ? 0.f : dec[b * 48000 + m * 600 + (t - 1)];
  }
  for (int idx = tid; idx < 256 * 80; idx += 256) {
    int j = idx / 80, k = idx - j * 80;
    sw1[j][k] = __float2bfloat16(Wp1[idx]);
  }
  __syncthreads();
  uint32_t ka, kb, ka2, kb2;
  dropout_keys(ka, kb, ka2, kb2);
  const int b  = tid & 63;
  const int jg = tid >> 6;
  for (int jj = 0; jj < 64; ++jj) {
    const int j = jg * 64 + jj;
    float acc = 0.f;
    #pragma unroll
    for (int k = 0; k < 80; ++k)
      acc += sdec[b][k] * __bfloat162float(sw1[j][k]);
    const uint32_t e = (uint32_t)((t * 64 + b) * 256 + j);
    pn1[(t * 64 + b) * 256 + j] =
        keep_mask(ka, kb, e) ? 2.f * fmaxf(acc, 0.f) : 0.f;
  }
}

// ---------------- prenet layer 2 -> X[t][b][0..255] (bf16) ------------------
__global__ void prenet2_kernel(const float* __restrict__ pn1,
                               const float* __restrict__ Wp2,
                               __hip_bfloat16* __restrict__ X) {
  const int t  = blockIdx.x;
  const int j0 = blockIdx.y * 32;
  const int tid = threadIdx.x;
  __shared__ __hip_bfloat16 sact[64][258];
  __shared__ __hip_bfloat16 sw[32][256];
  for (int idx = tid; idx < 64 * 256; idx += 256) {
    int b = idx >> 8, k = idx & 255;
    sact[b][k] = __float2bfloat16(pn1[(t * 64 + b) * 256 + k]);
  }
  for (int idx = tid; idx < 32 * 256; idx += 256) {
    int r = idx >> 8, k = idx & 255;
    sw[r][k] = __float2bfloat16(Wp2[(j0 + r) * 256 + k]);
  }
  __syncthreads();
  uint32_t ka, kb, ka2, kb2;
  dropout_keys(ka, kb, ka2, kb2);
  const int b  = tid & 63;
  const int jg = tid >> 6;
  float acc[8];
  #pragma unroll
  for (int c = 0; c < 8; ++c) acc[c] = 0.f;
  for (int k = 0; k < 256; ++k) {
    const float a = __bfloat162float(sact[b][k]);
    #pragma unroll
    for (int c = 0; c < 8; ++c)
      acc[c] += a * __bfloat162float(sw[jg * 8 + c][k]);
  }
  #pragma unroll
  for (int c = 0; c < 8; ++c) {
    const int j = j0 + jg * 8 + c;
    const uint32_t e = (uint32_t)((t * 64 + b) * 256 + j);
    const float v = keep_mask(ka2, kb2, e) ? 2.f * fmaxf(acc[c], 0.f) : 0.f;
    X[(t * 64 + b) * 1024 + j] = __float2bfloat16(v);
  }
}

// ---------------- X[t][b][256..799] = dur[b][t][:], [800..1023] = 0 ---------
__global__ void xfill_kernel(const float* __restrict__ dur,
                             __hip_bfloat16* __restrict__ X) {
  const int idx = blockIdx.x * 256 + threadIdx.x;
  const int t  = idx / 49152;
  const int r  = idx - t * 49152;
  const int b  = r / 768;
  const int kk = r - b * 768;
  const float v = (kk < 544) ? dur[(b * 600 + t) * 544 + kk] : 0.f;
  X[(t * 64 + b) * 1024 + 256 + kk] = __float2bfloat16(v);
}

__global__ void wprojcvt_kernel(const float* __restrict__ W,
                                __hip_bfloat16* __restrict__ Wb) {
  const int idx = blockIdx.x * 256 + threadIdx.x;
  Wb[idx] = __float2bfloat16(W[idx]);
}

// ---------------- persistent pipelined recurrence ---------------------------
__launch_bounds__(512, 2)
__global__ void persist_kernel(
    const float* __restrict__ Wih1, const float* __restrict__ Whh1,
    const float* __restrict__ bih1, const float* __restrict__ bhh1,
    const float* __restrict__ Wih2, const float* __restrict__ Whh2,
    const float* __restrict__ bih2, const float* __restrict__ bhh2,
    const __hip_bfloat16* __restrict__ WprojB, const float* __restrict__ bproj,
    const __hip_bfloat16* __restrict__ Xbuf,
    uint32_t* __restrict__ P0, uint32_t* __restrict__ P1,       // bf16-pair rings
    __hip_bfloat16* __restrict__ h1buf, __hip_bfloat16* __restrict__ h2buf,
    __hip_bfloat16* __restrict__ stagH1, __hip_bfloat16* __restrict__ stagH2,
    uint32_t* __restrict__ hflag1, uint32_t* __restrict__ hflag2,
    uint32_t* __restrict__ elect,
    uint32_t* __restrict__ flags,
    float* __restrict__ out) {
  const int bid  = blockIdx.x;
  const int role = bid >> 6;          // 0:AX 1:AF 2:B1 3:BF
  const int sub  = bid & 63;
  const int tid  = threadIdx.x;
  const int wave = tid >> 6;          // 8 waves
  const int lane = tid & 63;
  const int mh   = wave & 1;          // batch half
  const int kseg = wave >> 1;         // K quarter (256)

  __shared__ float pbuf[2][32][64];   // reduced gates [mh][m][n]
  __shared__ float sbuf[8][8];        // proj cross-wave partials
  __shared__ int   s_rank;

  // ---- physical-XCD identification + leader election ----
  uint32_t xcc;
  asm volatile("s_getreg_b32 %0, hwreg(HW_REG_XCC_ID, 0, 32)" : "=s"(xcc));
  xcc &= 7u;
  if (tid == 0)
    s_rank = (int)__hip_atomic_fetch_add(&elect[xcc], 1u,
                                         __ATOMIC_RELAXED, __HIP_MEMORY_SCOPE_AGENT);
  // per-XCD staging ring bases (consumers read ONLY their own XCD's copy)
  __hip_bfloat16* myStagH1 = stagH1 + (size_t)xcc * (16 * 65536);
  __hip_bfloat16* myStagH2 = stagH2 + (size_t)xcc * (16 * 65536);

  // ---- persistent weight fragments (bf16, MFMA B layout) ----
  const float* Wsrc = (role == 0) ? Wih1 : (role == 1) ? Whh1
                    : (role == 2) ? Wih2 : Whh2;
  const int Ksrc  = (role == 0) ? 800 : 1024;
  const int nrow  = lane & 31;
  const int khalf = (lane >> 5) * 8;
  bf16x8 bfr[16][2];
  #pragma unroll
  for (int ks = 0; ks < 16; ++ks) {
    #pragma unroll
    for (int nt = 0; nt < 2; ++nt) {
      const int nloc = nt * 32 + nrow;
      const int g = (role == 1 || role == 3)
                  ? ((nloc >> 4) * 1024 + sub * 16 + (nloc & 15))
                  : (sub * 64 + nloc);
      const int k0 = kseg * 256 + ks * 16 + khalf;
      bf16x8 v;
      if (k0 + 8 <= Ksrc) {
        const float* wp = Wsrc + (size_t)g * (size_t)Ksrc + k0;
        #pragma unroll
        for (int j = 0; j < 8; ++j) v[j] = bf16bits(wp[j]);
      } else {
        #pragma unroll
        for (int j = 0; j < 8; ++j) v[j] = (short)0;
      }
      bfr[ks][nt] = v;
    }
  }

  // ---- bias registers (role 0/2 write path) ----
  float breg[8];
  if (role == 0 || role == 2) {
    const float* bi = (role == 0) ? bih1 : bih2;
    const float* bh = (role == 0) ? bhh1 : bhh2;
    const int c0 = (tid * 8) & 63;
    #pragma unroll
    for (int j = 0; j < 8; ++j) {
      const int g = sub * 64 + c0 + j;
      breg[j] = bi[g] + bh[g];
    }
  }

  __syncthreads();
  const int rank = s_rank;
  const bool isldr  = (rank < 4);
  const int  job_h  = rank >> 1;          // 0: h1, 1: h2
  const int  job_o  = (rank & 1) * 8192;  // u64 offset (64 KB half)

  float cst[2] = {0.f, 0.f};
  const int brow = mh * 32 + (lane & 31);

  for (int tau = 0; tau < 604; ++tau) {
    const int sl = tau & 1;
    const bool active =
        (role == 0) ? (tau <= 599) :
        (role == 1) ? (tau >= 1 && tau <= 600) :
        (role == 2) ? (tau >= 2 && tau <= 601) :
                      (tau >= 3 && tau <= 602);
    f32x16 acc0, acc1;
    #pragma unroll
    for (int i = 0; i < 16; ++i) { acc0[i] = 0.f; acc1[i] = 0.f; }

    if (active) {
      if (role == 0) {
        // X is read-only input: plain cached loads
        const bf16x8* ap = reinterpret_cast<const bf16x8*>(
            Xbuf + (size_t)tau * 65536 + brow * 1024 + kseg * 256 + khalf);
        #pragma unroll
        for (int ks = 0; ks < 16; ++ks) {
          const bf16x8 a = ap[ks * 2];
          acc0 = __builtin_amdgcn_mfma_f32_32x32x16_bf16(a, bfr[ks][0], acc0, 0, 0, 0);
          acc1 = __builtin_amdgcn_mfma_f32_32x32x16_bf16(a, bfr[ks][1], acc1, 0, 0, 0);
        }
      } else {
        // staged h (leader-written, same-XCD L2): sc0 loads, L1 bypassed
        const __hip_bfloat16* Asrc =
            ((role == 3) ? myStagH2 : myStagH1) +
            (size_t)((tau - 1) & 15) * 65536;
        const __hip_bfloat16* abase = Asrc + brow * 1024 + kseg * 256 + khalf;
        bf16x8 A[8];
        ld8_sc0(abase, A);
        #pragma unroll
        for (int ks = 0; ks < 8; ++ks) {
          acc0 = __builtin_amdgcn_mfma_f32_32x32x16_bf16(A[ks], bfr[ks][0], acc0, 0, 0, 0);
          acc1 = __builtin_amdgcn_mfma_f32_32x32x16_bf16(A[ks], bfr[ks][1], acc1, 0, 0, 0);
        }
        ld8_sc0(abase + 128, A);   // +256 B: ks 8..15
        #pragma unroll
        for (int ks = 0; ks < 8; ++ks) {
          acc0 = __builtin_amdgcn_mfma_f32_32x32x16_bf16(A[ks], bfr[ks + 8][0], acc0, 0, 0, 0);
          acc1 = __builtin_amdgcn_mfma_f32_32x32x16_bf16(A[ks], bfr[ks + 8][1], acc1, 0, 0, 0);
        }
      }
    }
    // ---- K-split partial reduction through LDS (4 rounds) ----
    #pragma unroll
    for (int r = 0; r < 4; ++r) {
      if (active && kseg == r) {
        #pragma unroll
        for (int reg = 0; reg < 16; ++reg) {
          const int mrow = (reg & 3) + 8 * (reg >> 2) + 4 * (lane >> 5);
          const int col  = lane & 31;
          if (r == 0) {
            pbuf[mh][mrow][col]      = acc0[reg];
            pbuf[mh][mrow][col + 32] = acc1[reg];
          } else {
            pbuf[mh][mrow][col]      += acc0[reg];
            pbuf[mh][mrow][col + 32] += acc1[reg];
          }
        }
      }
      __syncthreads();
    }
    // ---- consume ----
    if (active) {
      if (role == 0 || role == 2) {   // write P ring (bf16 pairs, bypass)
        uint32_t* Pd = ((role == 0) ? P0 : P1) + sl * 131072;
        const int i0 = tid * 8;
        const int b  = i0 >> 6;
        const int c0 = i0 & 63;
        uint32_t* dst = Pd + ((b * 4096 + sub * 64 + c0) >> 1);
        const float* pr = &pbuf[b >> 5][b & 31][0];
        #pragma unroll
        for (int j = 0; j < 4; ++j) {
          const uint32_t lo = (uint32_t)(uint16_t)bf16bits(pr[c0 + 2 * j]     + breg[2 * j]);
          const uint32_t hi = (uint32_t)(uint16_t)bf16bits(pr[c0 + 2 * j + 1] + breg[2 * j + 1]);
          st_u32_a(dst + j, lo | (hi << 16));
        }
      } else {                        // LSTM pointwise, publish h (bypass)
        __hip_bfloat16* hdst = (role == 1) ? h1buf : h2buf;   // single slot
        const uint32_t* Psrc = ((role == 1) ? P0 : P1) + ((tau + 1) & 1) * 131072;
        const int hcp = (tid & 7) * 2;
        const int b   = tid >> 3;
        const float* pr = &pbuf[b >> 5][b & 31][0];
        const uint32_t* q = Psrc + ((b * 4096 + sub * 16 + hcp) >> 1);
        const uint32_t pi = ld_u32_a(q);
        const uint32_t pf = ld_u32_a(q + 512);
        const uint32_t pg = ld_u32_a(q + 1024);
        const uint32_t po = ld_u32_a(q + 1536);
        const float gi0 = pr[hcp]      + bflo(pi), gi1 = pr[hcp + 1]      + bfhi(pi);
        const float gf0 = pr[16 + hcp] + bflo(pf), gf1 = pr[16 + hcp + 1] + bfhi(pf);
        const float gg0 = pr[32 + hcp] + bflo(pg), gg1 = pr[32 + hcp + 1] + bfhi(pg);
        const float go0 = pr[48 + hcp] + bflo(po), go1 = pr[48 + hcp + 1] + bfhi(po);
        const float c0n = sigf(gf0) * cst[0] + sigf(gi0) * tanhf2(gg0);
        const float c1n = sigf(gf1) * cst[1] + sigf(gi1) * tanhf2(gg1);
        cst[0] = c0n; cst[1] = c1n;
        const uint32_t h0 = (uint32_t)(uint16_t)bf16bits(sigf(go0) * tanhf2(c0n));
        const uint32_t h1v = (uint32_t)(uint16_t)bf16bits(sigf(go1) * tanhf2(c1n));
        st_u32_a(hdst + b * 1024 + sub * 16 + hcp, h0 | (h1v << 16));
      }
    }
    // ---- producer flags (h-stores drained by this syncthreads) ----
    __syncthreads();
    if (active && (role == 1 || role == 3) && tid == 0)
      st_u32_a(((role == 1) ? hflag1 : hflag2) + sub, (uint32_t)tau);

    // ---- projection out_{tau-4} (all blocks: 5 cols x 4 batch rows) ----
    const bool pact = (tau >= 4);
    if (pact) {
      const __hip_bfloat16* h2s = myStagH2 + (size_t)((tau - 1) & 15) * 65536; // h2_{tau-4}
      const __hip_bfloat16* xs  = Xbuf + (size_t)(tau - 4) * 65536;
      const int c0 = (bid & 15) * 5;
      const int b  = (bid >> 4) * 4 + (tid >> 7);
      const int kl = tid & 127;
      float pj[5];
      #pragma unroll
      for (int c = 0; c < 5; ++c) pj[c] = 0.f;
      // staged h2 rows: sc0 (L1-bypass) batch — k2 = kl*2 + {0,256,512,768}
      uint32_t hreg[4];
      ld4_u32_sc0(h2s + b * 1024 + kl * 2, hreg);
      #pragma unroll
      for (int i = 0; i < 4; ++i) {
        const int k2 = kl * 2 + i * 256;
        const float a0 = bflo(hreg[i]), a1 = bfhi(hreg[i]);
        #pragma unroll
        for (int c = 0; c < 5; ++c) {
          const uint32_t w = *(const uint32_t*)(WprojB + (c0 + c) * 1568 + k2);
          pj[c] += a0 * bflo(w) + a1 * bfhi(w);
        }
      }
      // X part (read-only, cached): k2 = kl*2 + {1024, 1280, (1536 if kl<16)}
      for (int k2 = kl * 2 + 1024; k2 < 1568; k2 += 256) {
        const uint32_t u = *(const uint32_t*)(xs + b * 1024 + (k2 - 768));
        const float a0 = bflo(u), a1 = bfhi(u);
        #pragma unroll
        for (int c = 0; c < 5; ++c) {
          const uint32_t w = *(const uint32_t*)(WprojB + (c0 + c) * 1568 + k2);
          pj[c] += a0 * bflo(w) + a1 * bfhi(w);
        }
      }
      #pragma unroll
      for (int c = 0; c < 5; ++c) {
        #pragma unroll
        for (int off = 32; off > 0; off >>= 1)
          pj[c] += __shfl_xor(pj[c], off, 64);
      }
      if (lane == 0) {
        #pragma unroll
        for (int c = 0; c < 5; ++c) sbuf[wave][c] = pj[c];
      }
    }
    __syncthreads();
    if (pact && ((wave & 1) == 0) && lane == 0) {
      const int c0 = (bid & 15) * 5;
      const int b  = (bid >> 4) * 4 + (wave >> 1);
      #pragma unroll
      for (int c = 0; c < 5; ++c)
        out[b * 48000 + (c0 + c) * 600 + (tau - 4)] =
            sbuf[wave][c] + sbuf[wave + 1][c] + bproj[c0 + c];
    }

    // ---- leader: pull published h from MALL into this XCD's staging ring ---
    if (isldr) {
      const bool cpact = job_h ? (tau >= 3 && tau <= 602)
                               : (tau >= 1 && tau <= 600);
      if (cpact) {
        if (wave == 0) {
          const uint32_t* hf = job_h ? hflag2 : hflag1;
          for (;;) {
            const uint32_t v = ld_u32_a(hf + lane);
            if (__all((int)(v >= (uint32_t)tau))) break;
            __builtin_amdgcn_s_sleep(1);
          }
        }
        __syncthreads();   // block-uniform branch
        const uint64_t* src =
            (const uint64_t*)(job_h ? h2buf : h1buf) + job_o;
        uint64_t* dst =
            (uint64_t*)(job_h ? myStagH2 : myStagH1) +
            (size_t)(tau & 15) * 16384 + job_o;
        #pragma unroll
        for (int j = 0; j < 16; ++j)
          dst[j * 512 + tid] = ld_u64_a(src + j * 512 + tid);   // cached store
      }
    }

    // ---- grid barrier: per-tau flag array, relaxed ops only ----
    __syncthreads();   // drains vmcnt: staging stores visible in this XCD's L2
    if (tid == 0) st_u32_a(flags + (size_t)tau * 256 + bid, 1u);
    if (wave == 0) {
      const uint32_t* f = flags + (size_t)tau * 256;
      for (;;) {
        const uint32_t a0 = ld_u32_a(f + lane);
        const uint32_t a1 = ld_u32_a(f + 64 + lane);
        const uint32_t a2 = ld_u32_a(f + 128 + lane);
        const uint32_t a3 = ld_u32_a(f + 192 + lane);
        if (__all((int)(a0 & a1 & a2 & a3))) break;
        __builtin_amdgcn_s_sleep(1);
      }
    }
    __syncthreads();
  }
}

// ---------------------------------------------------------------------------
extern "C" void kernel_launch(void* const* d_in, const int* in_sizes, int n_in,
                              void* d_out, int out_size, void* d_ws, size_t ws_size,
                              hipStream_t stream) {
  (void)in_sizes; (void)n_in; (void)out_size; (void)ws_size;
  const float* dur   = (const float*)d_in[0];   // [64][600][544]
  const float* dec   = (const float*)d_in[1];   // [64][80][600]
  const float* Wp1   = (const float*)d_in[3];
  const float* Wp2   = (const float*)d_in[4];
  const float* Wih1  = (const float*)d_in[5];
  const float* Whh1  = (const float*)d_in[6];
  const float* bih1  = (const float*)d_in[7];
  const float* bhh1  = (const float*)d_in[8];
  const float* Wih2  = (const float*)d_in[9];
  const float* Whh2  = (const float*)d_in[10];
  const float* bih2  = (const float*)d_in[11];
  const float* bhh2  = (const float*)d_in[12];
  const float* Wproj = (const float*)d_in[13];
  const float* bproj = (const float*)d_in[14];

  char* ws = (char*)d_ws;
  // layout:
  //   X    @ 0           : 600*64*1024*2 = 78,643,200
  //   WpjB @ 78,643,200  : 80*1568*2     =    250,880   -> ends 78,894,080
  //   comm @ 78,894,080  (memset to 0 AFTER prenet2; overlaps dead pn1):
  //     elect   +0          64 B
  //     hflag1  +64         256 B
  //     hflag2  +320        256 B
  //     flags   +576        604*256*4 = 618,496          -> 619,072
  //     h1buf   +619,072    64*1024*2 = 131,072          -> 750,144
  //     h2buf   +750,144    131,072                      -> 881,216
  //     P0      +881,216    2 slots * 64*4096*2 = 1,048,576  -> 1,929,792
  //     P1      +1,929,792  1,048,576                    -> 2,978,368
  //     stagH1  +2,978,368  8 XCD * 16 slots * 131,072 = 16,777,216 -> 19,755,584
  //     stagH2  +19,755,584 16,777,216                   -> 36,532,800
  //   pn1  @ 78,894,080  : 39,321,600 (dead after prenet2)
  __hip_bfloat16* X    = (__hip_bfloat16*)(ws + 0);
  __hip_bfloat16* WpjB = (__hip_bfloat16*)(ws + 78643200);
  char*           comm = ws + 78894080;
  uint32_t*       elect  = (uint32_t*)(comm + 0);
  uint32_t*       hflag1 = (uint32_t*)(comm + 64);
  uint32_t*       hflag2 = (uint32_t*)(comm + 320);
  uint32_t*       flags  = (uint32_t*)(comm + 576);
  __hip_bfloat16* h1     = (__hip_bfloat16*)(comm + 619072);
  __hip_bfloat16* h2     = (__hip_bfloat16*)(comm + 750144);
  uint32_t*       P0     = (uint32_t*)(comm + 881216);
  uint32_t*       P1     = (uint32_t*)(comm + 1929792);
  __hip_bfloat16* stagH1 = (__hip_bfloat16*)(comm + 2978368);
  __hip_bfloat16* stagH2 = (__hip_bfloat16*)(comm + 19755584);
  float*          pn1    = (float*)(ws + 78894080);

  prenet1_kernel<<<600, 256, 0, stream>>>(dec, Wp1, pn1);
  prenet2_kernel<<<dim3(600, 8), 256, 0, stream>>>(pn1, Wp2, X);
  // zero entire comm region (elect/flags/h/P/staging) after pn1 is consumed
  hipMemsetAsync(comm, 0, 36532800, stream);
  xfill_kernel<<<115200, 256, 0, stream>>>(dur, X);
  wprojcvt_kernel<<<490, 256, 0, stream>>>(Wproj, WpjB);
  persist_kernel<<<256, 512, 0, stream>>>(Wih1, Whh1, bih1, bhh1,
                                          Wih2, Whh2, bih2, bhh2,
                                          WpjB, bproj, X, P0, P1, h1, h2,
                                          stagH1, stagH2, hflag1, hflag2,
                                          elect, flags, (float*)d_out);
}

// Round 7
// 9279.190 us; speedup vs baseline: 1.4451x; 1.4451x over previous
//
#include <hip/hip_runtime.h>
#include <hip/hip_bf16.h>
#include <stdint.h>

// ---------------------------------------------------------------------------
// Tacotron2 decoder on MI355X — persistent pipelined recurrence, v7.
// v7 = R2's proven 4-role + grid-barrier structure, with every MALL access
// BATCHED via inline asm (N loads + ONE s_waitcnt, "sc0 sc1" = bypass L1+L2,
// coherent at MALL). Theory: __hip_atomic_load compiles to one serialized
// ~0.5us MALL round trip each (R2's 32-load consumer path = 16us/tick; R6's
// 16-load leader copy = 8us/tick). Leader/staging removed. P rings bf16 at
// the CORRECT size (2 x 524,288 B — the R3-R5 aliasing bug).
// ---------------------------------------------------------------------------

typedef short  bf16x8  __attribute__((ext_vector_type(8)));
typedef float  f32x16  __attribute__((ext_vector_type(16)));

// ---------------- threefry2x32 (exact JAX semantics) ------------------------
__device__ __forceinline__ uint32_t rotl32(uint32_t x, int r) {
  return (x << r) | (x >> (32 - r));
}

__device__ __forceinline__ void tf2x32(uint32_t k0, uint32_t k1,
                                       uint32_t x0, uint32_t x1,
                                       uint32_t& o0, uint32_t& o1) {
  uint32_t k2 = k0 ^ k1 ^ 0x1BD11BDAu;
  x0 += k0; x1 += k1;
#define TF_R(r) { x0 += x1; x1 = rotl32(x1, r); x1 ^= x0; }
  TF_R(13) TF_R(15) TF_R(26) TF_R(6)   x0 += k1; x1 += k2 + 1u;
  TF_R(17) TF_R(29) TF_R(16) TF_R(24)  x0 += k2; x1 += k0 + 2u;
  TF_R(13) TF_R(15) TF_R(26) TF_R(6)   x0 += k0; x1 += k1 + 3u;
  TF_R(17) TF_R(29) TF_R(16) TF_R(24)  x0 += k1; x1 += k2 + 4u;
  TF_R(13) TF_R(15) TF_R(26) TF_R(6)   x0 += k2; x1 += k0 + 5u;
#undef TF_R
  o0 = x0; o1 = x1;
}

__device__ __forceinline__ void dropout_keys(uint32_t& a1, uint32_t& b1,
                                             uint32_t& a2, uint32_t& b2) {
  uint32_t o0, o1, p0, p1;
  tf2x32(0u, 42u, 0u, 2u, o0, o1);
  tf2x32(0u, 42u, 1u, 3u, p0, p1);
  a1 = o0; b1 = p0;
  a2 = o1; b2 = p1;
}

__device__ __forceinline__ bool keep_mask(uint32_t ka, uint32_t kb, uint32_t e) {
  const uint32_t H = 4923392u;       // (601*64*256)/2
  uint32_t o0, o1;
  if (e < H) { tf2x32(ka, kb, e, e + H, o0, o1); return o0 < 0x80000000u; }
  else       { tf2x32(ka, kb, e - H, e, o0, o1); return o1 < 0x80000000u; }
}

__device__ __forceinline__ float sigf(float x)  { return 1.f / (1.f + __expf(-x)); }
__device__ __forceinline__ float tanhf2(float x){ return 2.f / (1.f + __expf(-2.f * x)) - 1.f; }

__device__ __forceinline__ short bf16bits(float f) {
  __hip_bfloat16 h = __float2bfloat16(f);
  short s; __builtin_memcpy(&s, &h, 2);
  return s;
}
__device__ __forceinline__ float bflo(uint32_t u) {
  uint32_t x = u << 16; float f; __builtin_memcpy(&f, &x, 4); return f;
}
__device__ __forceinline__ float bfhi(uint32_t u) {
  uint32_t x = u & 0xffff0000u; float f; __builtin_memcpy(&f, &x, 4); return f;
}

// ---- relaxed agent-scope single-word accessors (flags only) ----------------
__device__ __forceinline__ void st_u32_a(void* p, uint32_t v) {
  __hip_atomic_store((uint32_t*)p, v, __ATOMIC_RELAXED, __HIP_MEMORY_SCOPE_AGENT);
}

// ---- BATCHED MALL loads: sc0 sc1 = bypass L1+L2, served at coherent MALL.
// N loads in flight, ONE s_waitcnt — ~1 round trip instead of N. -------------
__device__ __forceinline__ void ld8_mall(const __hip_bfloat16* p, bf16x8 (&d)[8]) {
  asm volatile(
      "global_load_dwordx4 %0, %8, off sc0 sc1\n\t"
      "global_load_dwordx4 %1, %8, off offset:32 sc0 sc1\n\t"
      "global_load_dwordx4 %2, %8, off offset:64 sc0 sc1\n\t"
      "global_load_dwordx4 %3, %8, off offset:96 sc0 sc1\n\t"
      "global_load_dwordx4 %4, %8, off offset:128 sc0 sc1\n\t"
      "global_load_dwordx4 %5, %8, off offset:160 sc0 sc1\n\t"
      "global_load_dwordx4 %6, %8, off offset:192 sc0 sc1\n\t"
      "global_load_dwordx4 %7, %8, off offset:224 sc0 sc1\n\t"
      "s_waitcnt vmcnt(0)"
      : "=&v"(d[0]), "=&v"(d[1]), "=&v"(d[2]), "=&v"(d[3]),
        "=&v"(d[4]), "=&v"(d[5]), "=&v"(d[6]), "=&v"(d[7])
      : "v"(p) : "memory");
}
// 4 independent addresses (P gate reads: strides exceed the 13-bit imm range)
__device__ __forceinline__ void ld4_mall4(const uint32_t* p0, const uint32_t* p1,
                                          const uint32_t* p2, const uint32_t* p3,
                                          uint32_t (&d)[4]) {
  asm volatile(
      "global_load_dword %0, %4, off sc0 sc1\n\t"
      "global_load_dword %1, %5, off sc0 sc1\n\t"
      "global_load_dword %2, %6, off sc0 sc1\n\t"
      "global_load_dword %3, %7, off sc0 sc1\n\t"
      "s_waitcnt vmcnt(0)"
      : "=&v"(d[0]), "=&v"(d[1]), "=&v"(d[2]), "=&v"(d[3])
      : "v"(p0), "v"(p1), "v"(p2), "v"(p3) : "memory");
}
// 4 dwords at +0,+512,+1024,+1536 bytes (proj h2 rows)
__device__ __forceinline__ void ld4_mall_s512(const __hip_bfloat16* p,
                                              uint32_t (&d)[4]) {
  asm volatile(
      "global_load_dword %0, %4, off sc0 sc1\n\t"
      "global_load_dword %1, %4, off offset:512 sc0 sc1\n\t"
      "global_load_dword %2, %4, off offset:1024 sc0 sc1\n\t"
      "global_load_dword %3, %4, off offset:1536 sc0 sc1\n\t"
      "s_waitcnt vmcnt(0)"
      : "=&v"(d[0]), "=&v"(d[1]), "=&v"(d[2]), "=&v"(d[3])
      : "v"(p) : "memory");
}
// barrier poll: 4 dwords at +0,+256,+512,+768 bytes
__device__ __forceinline__ void ld4_flags(const uint32_t* p, uint32_t (&d)[4]) {
  asm volatile(
      "global_load_dword %0, %4, off sc0 sc1\n\t"
      "global_load_dword %1, %4, off offset:256 sc0 sc1\n\t"
      "global_load_dword %2, %4, off offset:512 sc0 sc1\n\t"
      "global_load_dword %3, %4, off offset:768 sc0 sc1\n\t"
      "s_waitcnt vmcnt(0)"
      : "=&v"(d[0]), "=&v"(d[1]), "=&v"(d[2]), "=&v"(d[3])
      : "v"(p) : "memory");
}

// ---------------- prenet layer 1 --------------------------------------------
__global__ void prenet1_kernel(const float* __restrict__ dec,
                               const float* __restrict__ Wp1,
                               float* __restrict__ pn1) {
  const int t = blockIdx.x;
  const int tid = threadIdx.x;
  __shared__ float          sdec[64][81];
  __shared__ __hip_bfloat16 sw1[256][80];
  for (int idx = tid; idx < 64 * 80; idx += 256) {
    int b = idx / 80, m = idx - b * 80;
    sdec[b][m] = (t == 0) ? 0.f : dec[b * 48000 + m * 600 + (t - 1)];
  }
  for (int idx = tid; idx < 256 * 80; idx += 256) {
    int j = idx / 80, k = idx - j * 80;
    sw1[j][k] = __float2bfloat16(Wp1[idx]);
  }
  __syncthreads();
  uint32_t ka, kb, ka2, kb2;
  dropout_keys(ka, kb, ka2, kb2);
  const int b  = tid & 63;
  const int jg = tid >> 6;
  for (int jj = 0; jj < 64; ++jj) {
    const int j = jg * 64 + jj;
    float acc = 0.f;
    #pragma unroll
    for (int k = 0; k < 80; ++k)
      acc += sdec[b][k] * __bfloat162float(sw1[j][k]);
    const uint32_t e = (uint32_t)((t * 64 + b) * 256 + j);
    pn1[(t * 64 + b) * 256 + j] =
        keep_mask(ka, kb, e) ? 2.f * fmaxf(acc, 0.f) : 0.f;
  }
}

// ---------------- prenet layer 2 -> X[t][b][0..255] (bf16) ------------------
__global__ void prenet2_kernel(const float* __restrict__ pn1,
                               const float* __restrict__ Wp2,
                               __hip_bfloat16* __restrict__ X) {
  const int t  = blockIdx.x;
  const int j0 = blockIdx.y * 32;
  const int tid = threadIdx.x;
  __shared__ __hip_bfloat16 sact[64][258];
  __shared__ __hip_bfloat16 sw[32][256];
  for (int idx = tid; idx < 64 * 256; idx += 256) {
    int b = idx >> 8, k = idx & 255;
    sact[b][k] = __float2bfloat16(pn1[(t * 64 + b) * 256 + k]);
  }
  for (int idx = tid; idx < 32 * 256; idx += 256) {
    int r = idx >> 8, k = idx & 255;
    sw[r][k] = __float2bfloat16(Wp2[(j0 + r) * 256 + k]);
  }
  __syncthreads();
  uint32_t ka, kb, ka2, kb2;
  dropout_keys(ka, kb, ka2, kb2);
  const int b  = tid & 63;
  const int jg = tid >> 6;
  float acc[8];
  #pragma unroll
  for (int c = 0; c < 8; ++c) acc[c] = 0.f;
  for (int k = 0; k < 256; ++k) {
    const float a = __bfloat162float(sact[b][k]);
    #pragma unroll
    for (int c = 0; c < 8; ++c)
      acc[c] += a * __bfloat162float(sw[jg * 8 + c][k]);
  }
  #pragma unroll
  for (int c = 0; c < 8; ++c) {
    const int j = j0 + jg * 8 + c;
    const uint32_t e = (uint32_t)((t * 64 + b) * 256 + j);
    const float v = keep_mask(ka2, kb2, e) ? 2.f * fmaxf(acc[c], 0.f) : 0.f;
    X[(t * 64 + b) * 1024 + j] = __float2bfloat16(v);
  }
}

// ---------------- X[t][b][256..799] = dur[b][t][:], [800..1023] = 0 ---------
__global__ void xfill_kernel(const float* __restrict__ dur,
                             __hip_bfloat16* __restrict__ X) {
  const int idx = blockIdx.x * 256 + threadIdx.x;
  const int t  = idx / 49152;
  const int r  = idx - t * 49152;
  const int b  = r / 768;
  const int kk = r - b * 768;
  const float v = (kk < 544) ? dur[(b * 600 + t) * 544 + kk] : 0.f;
  X[(t * 64 + b) * 1024 + 256 + kk] = __float2bfloat16(v);
}

__global__ void wprojcvt_kernel(const float* __restrict__ W,
                                __hip_bfloat16* __restrict__ Wb) {
  const int idx = blockIdx.x * 256 + threadIdx.x;
  Wb[idx] = __float2bfloat16(W[idx]);
}

// ---------------- persistent pipelined recurrence ---------------------------
__launch_bounds__(512, 2)
__global__ void persist_kernel(
    const float* __restrict__ Wih1, const float* __restrict__ Whh1,
    const float* __restrict__ bih1, const float* __restrict__ bhh1,
    const float* __restrict__ Wih2, const float* __restrict__ Whh2,
    const float* __restrict__ bih2, const float* __restrict__ bhh2,
    const __hip_bfloat16* __restrict__ WprojB, const float* __restrict__ bproj,
    const __hip_bfloat16* __restrict__ Xbuf,
    uint32_t* __restrict__ P0, uint32_t* __restrict__ P1,     // bf16-pair rings
    __hip_bfloat16* __restrict__ h1buf, __hip_bfloat16* __restrict__ h2buf,
    uint32_t* __restrict__ flags,
    float* __restrict__ out) {
  const int bid  = blockIdx.x;
  const int role = bid >> 6;          // 0:AX 1:AF 2:B1 3:BF
  const int sub  = bid & 63;
  const int tid  = threadIdx.x;
  const int wave = tid >> 6;          // 8 waves
  const int lane = tid & 63;
  const int mh   = wave & 1;          // batch half
  const int kseg = wave >> 1;         // K quarter (256)

  __shared__ float pbuf[2][32][64];   // reduced gates [mh][m][n]
  __shared__ float sbuf[8][8];        // proj cross-wave partials

  // ---- persistent weight fragments (bf16, MFMA B layout) ----
  const float* Wsrc = (role == 0) ? Wih1 : (role == 1) ? Whh1
                    : (role == 2) ? Wih2 : Whh2;
  const int Ksrc  = (role == 0) ? 800 : 1024;
  const int nrow  = lane & 31;
  const int khalf = (lane >> 5) * 8;
  bf16x8 bfr[16][2];
  #pragma unroll
  for (int ks = 0; ks < 16; ++ks) {
    #pragma unroll
    for (int nt = 0; nt < 2; ++nt) {
      const int nloc = nt * 32 + nrow;
      const int g = (role == 1 || role == 3)
                  ? ((nloc >> 4) * 1024 + sub * 16 + (nloc & 15))  // i/f/g/o interleave
                  : (sub * 64 + nloc);                             // natural slice
      const int k0 = kseg * 256 + ks * 16 + khalf;
      bf16x8 v;
      if (k0 + 8 <= Ksrc) {
        const float* wp = Wsrc + (size_t)g * (size_t)Ksrc + k0;
        #pragma unroll
        for (int j = 0; j < 8; ++j) v[j] = bf16bits(wp[j]);
      } else {
        #pragma unroll
        for (int j = 0; j < 8; ++j) v[j] = (short)0;
      }
      bfr[ks][nt] = v;
    }
  }

  // ---- bias registers (role 0/2 write path): 8 consecutive gate cols ------
  float breg[8];
  if (role == 0 || role == 2) {
    const float* bi = (role == 0) ? bih1 : bih2;
    const float* bh = (role == 0) ? bhh1 : bhh2;
    const int c0 = (tid * 8) & 63;
    #pragma unroll
    for (int j = 0; j < 8; ++j) {
      const int g = sub * 64 + c0 + j;
      breg[j] = bi[g] + bh[g];
    }
  }

  float cst[2] = {0.f, 0.f};          // c-state: (b = tid>>3, cols hcp, hcp+1)
  const int brow = mh * 32 + (lane & 31);

  for (int tau = 0; tau < 604; ++tau) {
    const int sl = tau & 1;
    const bool active =
        (role == 0) ? (tau <= 599) :
        (role == 1) ? (tau >= 1 && tau <= 600) :
        (role == 2) ? (tau >= 2 && tau <= 601) :
                      (tau >= 3 && tau <= 602);
    f32x16 acc0, acc1;
    #pragma unroll
    for (int i = 0; i < 16; ++i) { acc0[i] = 0.f; acc1[i] = 0.f; }

    uint32_t pg4[4] = {0u, 0u, 0u, 0u};   // prefetched P gate pairs (roles 1/3)

    if (active) {
      if (role == 0) {
        // X is read-only input: plain cached loads
        const bf16x8* ap = reinterpret_cast<const bf16x8*>(
            Xbuf + (size_t)tau * 65536 + brow * 1024 + kseg * 256 + khalf);
        #pragma unroll
        for (int ks = 0; ks < 16; ++ks) {
          const bf16x8 a = ap[ks * 2];
          acc0 = __builtin_amdgcn_mfma_f32_32x32x16_bf16(a, bfr[ks][0], acc0, 0, 0, 0);
          acc1 = __builtin_amdgcn_mfma_f32_32x32x16_bf16(a, bfr[ks][1], acc1, 0, 0, 0);
        }
      } else {
        // prefetch P gates for the pointwise stage (roles 1/3) — one batch
        if (role & 1) {
          const uint32_t* Psrc = ((role == 1) ? P0 : P1) + ((tau + 1) & 1) * 131072;
          const int hcp = (tid & 7) * 2;
          const int pb  = tid >> 3;
          const uint32_t* q = Psrc + ((pb * 4096 + sub * 16 + hcp) >> 1);
          ld4_mall4(q, q + 512, q + 1024, q + 1536, pg4);
        }
        // h ring (cross-block comm) — two 8-load batches from MALL
        const __hip_bfloat16* Asrc =
            ((role == 3) ? h2buf : h1buf) + sl * 65536;
        const __hip_bfloat16* abase = Asrc + brow * 1024 + kseg * 256 + khalf;
        bf16x8 A[8];
        ld8_mall(abase, A);
        #pragma unroll
        for (int ks = 0; ks < 8; ++ks) {
          acc0 = __builtin_amdgcn_mfma_f32_32x32x16_bf16(A[ks], bfr[ks][0], acc0, 0, 0, 0);
          acc1 = __builtin_amdgcn_mfma_f32_32x32x16_bf16(A[ks], bfr[ks][1], acc1, 0, 0, 0);
        }
        ld8_mall(abase + 128, A);   // +256 B: ks 8..15
        #pragma unroll
        for (int ks = 0; ks < 8; ++ks) {
          acc0 = __builtin_amdgcn_mfma_f32_32x32x16_bf16(A[ks], bfr[ks + 8][0], acc0, 0, 0, 0);
          acc1 = __builtin_amdgcn_mfma_f32_32x32x16_bf16(A[ks], bfr[ks + 8][1], acc1, 0, 0, 0);
        }
      }
    }
    // ---- K-split partial reduction through LDS (4 rounds) ----
    #pragma unroll
    for (int r = 0; r < 4; ++r) {
      if (active && kseg == r) {
        #pragma unroll
        for (int reg = 0; reg < 16; ++reg) {
          const int mrow = (reg & 3) + 8 * (reg >> 2) + 4 * (lane >> 5);
          const int col  = lane & 31;
          if (r == 0) {
            pbuf[mh][mrow][col]      = acc0[reg];
            pbuf[mh][mrow][col + 32] = acc1[reg];
          } else {
            pbuf[mh][mrow][col]      += acc0[reg];
            pbuf[mh][mrow][col + 32] += acc1[reg];
          }
        }
      }
      __syncthreads();
    }
    // ---- consume ----
    if (active) {
      if (role == 0 || role == 2) {   // write P ring (bf16 pairs, bypass)
        uint32_t* Pd = ((role == 0) ? P0 : P1) + sl * 131072;
        const int i0 = tid * 8;
        const int b  = i0 >> 6;
        const int c0 = i0 & 63;
        uint32_t* dst = Pd + ((b * 4096 + sub * 64 + c0) >> 1);
        const float* pr = &pbuf[b >> 5][b & 31][0];
        #pragma unroll
        for (int j = 0; j < 4; ++j) {
          const uint32_t lo = (uint32_t)(uint16_t)bf16bits(pr[c0 + 2 * j]     + breg[2 * j]);
          const uint32_t hi = (uint32_t)(uint16_t)bf16bits(pr[c0 + 2 * j + 1] + breg[2 * j + 1]);
          st_u32_a(dst + j, lo | (hi << 16));
        }
      } else {                        // LSTM pointwise with prefetched gates
        __hip_bfloat16* hdst =
            ((role == 1) ? h1buf : h2buf) + ((tau + 1) & 1) * 65536;
        const int hcp = (tid & 7) * 2;
        const int b   = tid >> 3;
        const float* pr = &pbuf[b >> 5][b & 31][0];
        const float gi0 = pr[hcp]      + bflo(pg4[0]), gi1 = pr[hcp + 1]      + bfhi(pg4[0]);
        const float gf0 = pr[16 + hcp] + bflo(pg4[1]), gf1 = pr[16 + hcp + 1] + bfhi(pg4[1]);
        const float gg0 = pr[32 + hcp] + bflo(pg4[2]), gg1 = pr[32 + hcp + 1] + bfhi(pg4[2]);
        const float go0 = pr[48 + hcp] + bflo(pg4[3]), go1 = pr[48 + hcp + 1] + bfhi(pg4[3]);
        const float c0n = sigf(gf0) * cst[0] + sigf(gi0) * tanhf2(gg0);
        const float c1n = sigf(gf1) * cst[1] + sigf(gi1) * tanhf2(gg1);
        cst[0] = c0n; cst[1] = c1n;
        const uint32_t h0 = (uint32_t)(uint16_t)bf16bits(sigf(go0) * tanhf2(c0n));
        const uint32_t h1v = (uint32_t)(uint16_t)bf16bits(sigf(go1) * tanhf2(c1n));
        st_u32_a(hdst + b * 1024 + sub * 16 + hcp, h0 | (h1v << 16));
      }
    }
    // ---- projection out_{tau-4} (all blocks: 5 cols x 4 batch rows) ----
    const bool pact = (tau >= 4);
    if (pact) {
      const __hip_bfloat16* h2s = h2buf + sl * 65536;           // h2_{tau-4}
      const __hip_bfloat16* xs  = Xbuf + (size_t)(tau - 4) * 65536;
      const int c0 = (bid & 15) * 5;
      const int b  = (bid >> 4) * 4 + (tid >> 7);
      const int kl = tid & 127;
      float pj[5];
      #pragma unroll
      for (int c = 0; c < 5; ++c) pj[c] = 0.f;
      // h2 rows from MALL: one 4-load batch (k2 = kl*2 + {0,256,512,768})
      uint32_t hreg[4];
      ld4_mall_s512(h2s + b * 1024 + kl * 2, hreg);
      #pragma unroll
      for (int i = 0; i < 4; ++i) {
        const int k2 = kl * 2 + i * 256;
        const float a0 = bflo(hreg[i]), a1 = bfhi(hreg[i]);
        #pragma unroll
        for (int c = 0; c < 5; ++c) {
          const uint32_t w = *(const uint32_t*)(WprojB + (c0 + c) * 1568 + k2);
          pj[c] += a0 * bflo(w) + a1 * bfhi(w);
        }
      }
      // X part (read-only, cached): k2 = kl*2 + {1024, 1280, (1536 if kl<16)}
      for (int k2 = kl * 2 + 1024; k2 < 1568; k2 += 256) {
        const uint32_t u = *(const uint32_t*)(xs + b * 1024 + (k2 - 768));
        const float a0 = bflo(u), a1 = bfhi(u);
        #pragma unroll
        for (int c = 0; c < 5; ++c) {
          const uint32_t w = *(const uint32_t*)(WprojB + (c0 + c) * 1568 + k2);
          pj[c] += a0 * bflo(w) + a1 * bfhi(w);
        }
      }
      #pragma unroll
      for (int c = 0; c < 5; ++c) {
        #pragma unroll
        for (int off = 32; off > 0; off >>= 1)
          pj[c] += __shfl_xor(pj[c], off, 64);
      }
      if (lane == 0) {
        #pragma unroll
        for (int c = 0; c < 5; ++c) sbuf[wave][c] = pj[c];
      }
    }
    __syncthreads();
    if (pact && ((wave & 1) == 0) && lane == 0) {
      const int c0 = (bid & 15) * 5;
      const int b  = (bid >> 4) * 4 + (wave >> 1);
      #pragma unroll
      for (int c = 0; c < 5; ++c)
        out[b * 48000 + (c0 + c) * 600 + (tau - 4)] =
            sbuf[wave][c] + sbuf[wave + 1][c] + bproj[c0 + c];
    }
    // ---- grid barrier: per-tau flag array; batched poll (1 RT per round) ---
    __syncthreads();   // drains vmcnt: this block's bypass stores complete
    if (tid == 0) st_u32_a(flags + (size_t)tau * 256 + bid, 1u);
    if (wave == 0) {
      const uint32_t* f = flags + (size_t)tau * 256 + lane;
      for (;;) {
        uint32_t a[4];
        ld4_flags(f, a);
        if (__all((int)(a[0] & a[1] & a[2] & a[3]))) break;
        __builtin_amdgcn_s_sleep(2);
      }
    }
    __syncthreads();
  }
}

// ---------------------------------------------------------------------------
extern "C" void kernel_launch(void* const* d_in, const int* in_sizes, int n_in,
                              void* d_out, int out_size, void* d_ws, size_t ws_size,
                              hipStream_t stream) {
  (void)in_sizes; (void)n_in; (void)out_size; (void)ws_size;
  const float* dur   = (const float*)d_in[0];   // [64][600][544]
  const float* dec   = (const float*)d_in[1];   // [64][80][600]
  const float* Wp1   = (const float*)d_in[3];
  const float* Wp2   = (const float*)d_in[4];
  const float* Wih1  = (const float*)d_in[5];
  const float* Whh1  = (const float*)d_in[6];
  const float* bih1  = (const float*)d_in[7];
  const float* bhh1  = (const float*)d_in[8];
  const float* Wih2  = (const float*)d_in[9];
  const float* Whh2  = (const float*)d_in[10];
  const float* bih2  = (const float*)d_in[11];
  const float* bhh2  = (const float*)d_in[12];
  const float* Wproj = (const float*)d_in[13];
  const float* bproj = (const float*)d_in[14];

  char* ws = (char*)d_ws;
  // layout:
  //   X    @ 0           : 600*64*1024*2 = 78,643,200
  //   WpjB @ 78,643,200  : 80*1568*2     =    250,880   -> ends 78,894,080
  //   comm @ 78,894,080  (memset to 0 AFTER prenet2; overlaps dead pn1):
  //     flags  +0          604*256*4 = 618,496          -> 618,496
  //     h1buf  +618,496    2 slots * 64*1024*2 = 262,144 -> 880,640
  //     h2buf  +880,640    262,144                      -> 1,142,784
  //     P0     +1,142,784  2 slots * 64*4096*2 = 1,048,576 -> 2,191,360
  //     P1     +2,191,360  1,048,576                    -> 3,239,936
  //   pn1  @ 78,894,080  : 39,321,600 (dead after prenet2; covers comm)
  __hip_bfloat16* X    = (__hip_bfloat16*)(ws + 0);
  __hip_bfloat16* WpjB = (__hip_bfloat16*)(ws + 78643200);
  char*           comm = ws + 78894080;
  uint32_t*       flags= (uint32_t*)(comm + 0);
  __hip_bfloat16* h1   = (__hip_bfloat16*)(comm + 618496);
  __hip_bfloat16* h2   = (__hip_bfloat16*)(comm + 880640);
  uint32_t*       P0   = (uint32_t*)(comm + 1142784);
  uint32_t*       P1   = (uint32_t*)(comm + 2191360);
  float*          pn1  = (float*)(ws + 78894080);

  prenet1_kernel<<<600, 256, 0, stream>>>(dec, Wp1, pn1);
  prenet2_kernel<<<dim3(600, 8), 256, 0, stream>>>(pn1, Wp2, X);
  // zero comm region (flags/h/P) after pn1 is consumed
  hipMemsetAsync(comm, 0, 3239936, stream);
  xfill_kernel<<<115200, 256, 0, stream>>>(dur, X);
  wprojcvt_kernel<<<490, 256, 0, stream>>>(Wproj, WpjB);
  persist_kernel<<<256, 512, 0, stream>>>(Wih1, Whh1, bih1, bhh1,
                                          Wih2, Whh2, bih2, bhh2,
                                          WpjB, bproj, X, P0, P1, h1, h2,
                                          flags, (float*)d_out);
}